// Round 7
// baseline (542.488 us; speedup 1.0000x reference)
//
#include <hip/hip_runtime.h>

// PConvLinear: B=2, N=60000, K=16, C_in=64, C_add=3, C_mid=16.
// Round 7: wave-specialized persistent pipeline.
//   250 blocks x 512 thr; 15 tiles of 32 points per block.
//   waves 4-7 = PRODUCERS: 8 pts each, gather (inF16 f16x4 + Wn) held in
//     registers one full tile ahead; pconv via mfma 16x16x16f16 -> sP.
//   waves 0-3 = CONSUMERS: o-tile w*32; Phase B = mfma_f32_32x32x16_f16
//     (M=32 pts, N=32 o, K=16): ONE ds_read_b128 a-frag per 32k FLOP
//     (halves LDS reads), no K-split reduction, 2 parity acc chains.
//   sP row-XOR swizzle (byte ^= ((row>>3)&3)<<4, both sides) -> a-reads
//     are 4-phase conflict-ideal. One barrier/iter; producer tile t
//     overlaps consumer tile t-1.
#define NPTS  60000
#define NBLK  1875          // 32-pt tiles per batch
#define FP    1088          // F padded to 68*16
#define PSTR  1096          // sP row stride (f16)
#define ROWB  (PSTR * 2)    // 2192 B per sP row
#define HALFB (32 * ROWB)   // 70,144 B per buffer
#define SPBYTES    (2 * HALFB)         // 140,288 B
#define SPBYTES_FB HALFB               // fallback
#define LWH_BYTES   (128 * FP * 2)     // 278,528 B
#define INF16_BYTES (2 * NPTS * 64 * 2)
#define WS_NEED     (LWH_BYTES + INF16_BYTES)
#define TILES   15
#define NBLOCKS 250

typedef _Float16 f16x4 __attribute__((ext_vector_type(4)));
typedef _Float16 f16x8 __attribute__((ext_vector_type(8)));
typedef float    f32x4 __attribute__((ext_vector_type(4)));
typedef float    f32x16 __attribute__((ext_vector_type(16)));

// ---- pre-kernel (main path): LW fp32 [128][1072] -> LWB[ch=68][hf=2][o=128][8]
// b-frag for 32x32x16: lane l gets o = o0+(l&31), k-half hf = l>>5, 8 consec f16.
__global__ void __launch_bounds__(256)
cvt_lwb_kernel(const float* __restrict__ LW, _Float16* __restrict__ LWB) {
    const int o = blockIdx.x;
    for (int f = threadIdx.x; f < FP; f += 256) {
        const float v = (f < 1072) ? LW[o * 1072 + f] : 0.f;
        LWB[(f >> 3) * 1024 + o * 8 + (f & 7)] = (_Float16)v;
    }
}

// ---- pre-kernel (fallback path): old LWh2[ch=34][o=128][e=32] layout
__global__ void __launch_bounds__(256)
cvt_lw_kernel(const float* __restrict__ LW, _Float16* __restrict__ LWh) {
    const int o = blockIdx.x;
    for (int f = threadIdx.x; f < FP; f += 256) {
        const float v = (f < 1072) ? LW[o * 1072 + f] : 0.f;
        LWh[(f >> 5) * (128 * 32) + o * 32 + (f & 31)] = (_Float16)v;
    }
}

// ---- pre-kernel: inF fp32 [2N][64] -> f16 lane-packed: c=ct*16+ml at slot ml*4+ct
__global__ void __launch_bounds__(256)
cvt_inf_kernel(const float* __restrict__ inF, _Float16* __restrict__ inF16) {
    const int tid = blockIdx.x * 256 + threadIdx.x;
    if (tid >= 2 * NPTS * 64) return;
    const int c = tid & 63;
    const int n = tid >> 6;
    inF16[(n << 6) + ((c & 15) << 2) + (c >> 4)] = (_Float16)inF[tid];
}

__global__ void __launch_bounds__(512, 2)
pconv_persistent(const _Float16* __restrict__ inF16, // lane-packed f16 (d_ws)
                 const int*   __restrict__ inds,     // [2][60000][16]
                 const float* __restrict__ Wn,       // [2][60000][16][16]
                 const float* __restrict__ addF,     // [2][60000][16][3]
                 const _Float16* __restrict__ LWB,   // [68][2][128][8] f16 (d_ws)
                 const float* __restrict__ bias,     // [128]
                 float*       __restrict__ out)      // [2][60000][128]
{
    extern __shared__ __align__(16) char sPB[];   // 2 x [32 rows][ROWB]

    const int t    = threadIdx.x;
    const int lane = t & 63;
    const int w    = t >> 6;        // wave 0..7
    const int q    = lane >> 4;
    const int ml   = lane & 15;
    const bool mlo = (ml < 3);
    const int qsw  = q ^ (((ml >> 2) & 1) << 1);
    const int gt0  = blockIdx.x * TILES;

    // zero pad slots f in [1072,1088) of both buffers (swizzle-consistent, once)
    {
        const int row = t >> 4, jj = t & 15;
        const int zb = (2144 + 2 * jj) ^ (((row >> 3) & 3) << 4);
        *(_Float16*)(sPB + row * ROWB + zb) = (_Float16)0.f;
        *(_Float16*)(sPB + HALFB + row * ROWB + zb) = (_Float16)0.f;
    }

    if (w < 4) {
        // ================= CONSUMER: o-tile o0 = w*32 =================
        const int col = lane & 31;          // = o offset AND a-row (point)
        const int hf  = lane >> 5;          // k-half
        const int o0  = w * 32;
        const float bz = bias[o0 + col];
        const int rsw = ((col >> 3) & 3) << 4;   // row-XOR for a-reads
        const _Float16* bp0 = LWB + hf * 1024 + (o0 + col) * 8;

        for (int tt = 0; tt <= TILES; ++tt) {
            if (tt >= 1) {
                const int g  = gt0 + tt - 1;
                const int b  = g / NBLK;
                const int n0 = (g - b * NBLK) * 32;
                const int bb = b * NPTS;
                const char* aBase = sPB + ((tt - 1) & 1) * HALFB + col * ROWB;

                f32x16 acc0, acc1;
                #pragma unroll
                for (int i = 0; i < 16; ++i) { acc0[i] = 0.f; acc1[i] = 0.f; }

                f16x8 cur[4], nxt[4];
                #pragma unroll
                for (int u = 0; u < 4; ++u)
                    cur[u] = *(const f16x8*)(bp0 + u * 2048);

                for (int grp = 0; grp < 17; ++grp) {
                    #pragma unroll
                    for (int u = 0; u < 4; ++u)
                        if (grp < 16)
                            nxt[u] = *(const f16x8*)(bp0 + ((grp + 1) * 4 + u) * 2048);
                    #pragma unroll
                    for (int u = 0; u < 4; ++u) {
                        const int ch = grp * 4 + u;
                        const int ab = (ch * 32 + ((hf ^ ((ch >> 2) & 1)) << 4)) ^ rsw;
                        const f16x8 a = *(const f16x8*)(aBase + ab);  // ds_read_b128
                        if (u & 1)
                            acc1 = __builtin_amdgcn_mfma_f32_32x32x16_f16(a, cur[u], acc1, 0, 0, 0);
                        else
                            acc0 = __builtin_amdgcn_mfma_f32_32x32x16_f16(a, cur[u], acc0, 0, 0, 0);
                    }
                    #pragma unroll
                    for (int u = 0; u < 4; ++u) cur[u] = nxt[u];
                }

                // D layout 32x32: col = lane&31, row = (reg&3)+8*(reg>>2)+4*hf
                float* ob = out + (bb + n0) * 128 + o0 + col;
                #pragma unroll
                for (int reg = 0; reg < 16; ++reg) {
                    const int row = (reg & 3) + 8 * (reg >> 2) + 4 * hf;
                    ob[row * 128] = acc0[reg] + acc1[reg] + bz;
                }
            }
            __syncthreads();
        }
    } else {
        // ================= PRODUCER: points pw*8 .. pw*8+7 =================
        const int pw = w - 4;
        const f32x4 z4 = {0.f, 0.f, 0.f, 0.f};
        f16x4 fv[8][4];     // gathered inF16 frags, one tile in flight (64 VGPR)
        float wv[8][4];     // Wn values, one tile in flight (32 VGPR)

        int bbC, n0C, nkC;
        {
            const int g = gt0; const int b = g / NBLK;
            n0C = (g - b * NBLK) * 32; bbC = b * NPTS;
            nkC = (bbC + n0C + pw * 8) * 16;
        }
        // prologue: tile-0 gathers
        {
            const int i0 = inds[nkC + lane];
            const int i1 = inds[nkC + 64 + lane];
            #pragma unroll
            for (int p = 0; p < 8; ++p) {
                const int src = (p < 4) ? i0 : i1;
                #pragma unroll
                for (int j = 0; j < 4; ++j) {
                    const int idx = __shfl(src, (p & 3) * 16 + q * 4 + j, 64);
                    fv[p][j] = *(const f16x4*)(inF16 + (bbC + idx) * 64 + ml * 4);
                    wv[p][j] = Wn[(nkC + p * 16 + q * 4 + j) * 16 + ml];
                }
            }
        }

        for (int tt = 0; tt <= TILES; ++tt) {
            if (tt < TILES) {
                const bool more = (tt + 1 < TILES);
                int bbN = 0, n0N = 0, nkN = 0, iN0 = 0, iN1 = 0;
                if (more) {
                    const int g = gt0 + tt + 1; const int b = g / NBLK;
                    n0N = (g - b * NBLK) * 32; bbN = b * NPTS;
                    nkN = (bbN + n0N + pw * 8) * 16;
                    iN0 = inds[nkN + lane];
                    iN1 = inds[nkN + 64 + lane];
                }
                char* bufB = sPB + (tt & 1) * HALFB;

                #pragma unroll
                for (int p = 0; p < 8; ++p) {
                    // ---- compute point p of tile tt (pconv row -> sP) ----
                    const int bnk = nkC + p * 16;
                    f16x4 aW, bA;
                    #pragma unroll
                    for (int j = 0; j < 4; ++j) {
                        aW[j] = (_Float16)wv[p][j];
                        bA[j] = mlo ? (_Float16)addF[(bnk + q * 4 + j) * 3 + ml]
                                    : (_Float16)0.f;
                    }
                    const int prow = pw * 8 + p;
                    char* rowp = bufB + prow * ROWB;
                    const int rs2 = ((prow >> 3) & 3) << 4;
                    #pragma unroll
                    for (int ct = 0; ct < 4; ++ct) {
                        f16x4 bF;
                        #pragma unroll
                        for (int j = 0; j < 4; ++j) bF[j] = fv[p][j][ct];
                        const f32x4 d = __builtin_amdgcn_mfma_f32_16x16x16f16(aW, bF, z4, 0, 0, 0);
                        f16x4 dh;
                        #pragma unroll
                        for (int r = 0; r < 4; ++r) dh[r] = (_Float16)d[r];
                        *(f16x4*)(rowp + ((((ct * 16 + ml) * 16 + qsw * 4) * 2) ^ rs2)) = dh;
                    }
                    {   // c-tile 4: c = 64+ml (ml<3); qsw==q there
                        const f32x4 d = __builtin_amdgcn_mfma_f32_16x16x16f16(aW, bA, z4, 0, 0, 0);
                        if (mlo) {
                            f16x4 dh;
                            #pragma unroll
                            for (int r = 0; r < 4; ++r) dh[r] = (_Float16)d[r];
                            *(f16x4*)(rowp + ((((64 + ml) * 16 + qsw * 4) * 2) ^ rs2)) = dh;
                        }
                    }
                    // ---- refill p for tile tt+1 (in flight across Phase B) ----
                    if (more) {
                        const int src = (p < 4) ? iN0 : iN1;
                        #pragma unroll
                        for (int j = 0; j < 4; ++j) {
                            const int idx = __shfl(src, (p & 3) * 16 + q * 4 + j, 64);
                            fv[p][j] = *(const f16x4*)(inF16 + (bbN + idx) * 64 + ml * 4);
                            wv[p][j] = Wn[(nkN + p * 16 + q * 4 + j) * 16 + ml];
                        }
                    }
                }
                if (more) { bbC = bbN; n0C = n0N; nkC = nkN; }
            }
            __syncthreads();
        }
    }
}

// ================= fallback (ws too small): round-5 fp32-gather kernel =========
struct GR32 { float fv[4][4]; float wv[4]; float av[4]; };

static __device__ __forceinline__ void issue_gather32(
    const float* __restrict__ inF, const float* __restrict__ Wn,
    const float* __restrict__ addF, int bbase, int base_nk,
    int ind_lane, int i, int q, int ml, bool mlo, GR32& g)
{
    #pragma unroll
    for (int j = 0; j < 4; ++j) {
        const int k   = q * 4 + j;
        const int idx = __shfl(ind_lane, i * 16 + k, 64);
        const float* fp = inF + (bbase + idx) * 64 + ml;
        #pragma unroll
        for (int ct = 0; ct < 4; ++ct)
            g.fv[ct][j] = fp[ct * 16];
        g.wv[j] = Wn[(base_nk + k) * 16 + ml];
        g.av[j] = mlo ? addF[(base_nk + k) * 3 + ml] : 0.f;
    }
}

static __device__ __forceinline__ void compute_point32(
    const GR32& g, _Float16* sProw, int qsw, int ml, bool mlo)
{
    const f32x4 z4 = {0.f, 0.f, 0.f, 0.f};
    f16x4 aW, bA;
    #pragma unroll
    for (int j = 0; j < 4; ++j) { aW[j] = (_Float16)g.wv[j]; bA[j] = (_Float16)g.av[j]; }
    #pragma unroll
    for (int ct = 0; ct < 4; ++ct) {
        f16x4 bF;
        #pragma unroll
        for (int j = 0; j < 4; ++j) bF[j] = (_Float16)g.fv[ct][j];
        const f32x4 d = __builtin_amdgcn_mfma_f32_16x16x16f16(aW, bF, z4, 0, 0, 0);
        f16x4 dh;
        #pragma unroll
        for (int r = 0; r < 4; ++r) dh[r] = (_Float16)d[r];
        *(f16x4*)&sProw[(ct * 16 + ml) * 16 + qsw * 4] = dh;
    }
    const f32x4 d = __builtin_amdgcn_mfma_f32_16x16x16f16(aW, bA, z4, 0, 0, 0);
    if (mlo) {
        f16x4 dh;
        #pragma unroll
        for (int r = 0; r < 4; ++r) dh[r] = (_Float16)d[r];
        *(f16x4*)&sProw[(64 + ml) * 16 + qsw * 4] = dh;
    }
}

__global__ void __launch_bounds__(512, 4)
pconv_fallback(const float* __restrict__ inF, const int* __restrict__ inds,
               const float* __restrict__ Wn, const float* __restrict__ addF,
               const _Float16* __restrict__ LWh, const float* __restrict__ bias,
               float* __restrict__ out)
{
    extern __shared__ __align__(16) _Float16 sP[];
    const int t = threadIdx.x, lane = t & 63, w = t >> 6;
    const int q = lane >> 4, ml = lane & 15;
    const bool mlo = (ml < 3);
    const int qsw = q ^ (((ml >> 2) & 1) << 1);
    const int bid = blockIdx.x, b = bid / NBLK;
    const int n0 = (bid - b * NBLK) * 32, bbase = b * NPTS;
    const int ind_lane = inds[(bbase + n0 + w * 4) * 16 + lane];
    sP[(t >> 4) * PSTR + 1072 + (t & 15)] = (_Float16)0.f;

    const int nk0 = (bbase + n0 + w * 4) * 16;
    _Float16* sPw = sP + (w * 4) * PSTR;
    GR32 g0, g1;
    issue_gather32(inF, Wn, addF, bbase, nk0,      ind_lane, 0, q, ml, mlo, g0);
    issue_gather32(inF, Wn, addF, bbase, nk0 + 16, ind_lane, 1, q, ml, mlo, g1);
    compute_point32(g0, sPw,            qsw, ml, mlo);
    issue_gather32(inF, Wn, addF, bbase, nk0 + 32, ind_lane, 2, q, ml, mlo, g0);
    compute_point32(g1, sPw + PSTR,     qsw, ml, mlo);
    issue_gather32(inF, Wn, addF, bbase, nk0 + 48, ind_lane, 3, q, ml, mlo, g1);
    compute_point32(g0, sPw + 2 * PSTR, qsw, ml, mlo);
    compute_point32(g1, sPw + 3 * PSTR, qsw, ml, mlo);

    const int o0 = w * 16;
    const _Float16* bP = LWh + (o0 + ml) * 32 + q * 8;
    f16x8 bcur = *(const f16x8*)(bP);
    f16x8 bnxt = *(const f16x8*)(bP + 4096);
    __syncthreads();

    const float bz = bias[o0 + ml];
    f32x4 acc0 = {0.f, 0.f, 0.f, 0.f};
    f32x4 acc1 = {0.f, 0.f, 0.f, 0.f};
    const _Float16* aP0 = sP + ml * PSTR + (q >> 1) * 16 + (q & 1) * 8;
    const _Float16* aP1 = aP0 + 16 * PSTR;
    const int flip = (q & 1) ? -8 : 8;
    #pragma unroll 2
    for (int ch = 0; ch < 34; ++ch) {
        const int chf = (ch + 2 < 34) ? (ch + 2) : 33;
        f16x8 bfut = *(const f16x8*)(bP + chf * 4096);
        const int off = ch * 32 + ((ch & 2) ? flip : 0);
        f16x8 a0 = *(const f16x8*)(aP0 + off);
        f16x8 a1 = *(const f16x8*)(aP1 + off);
        acc0 = __builtin_amdgcn_mfma_f32_16x16x32_f16(a0, bcur, acc0, 0, 0, 0);
        acc1 = __builtin_amdgcn_mfma_f32_16x16x32_f16(a1, bcur, acc1, 0, 0, 0);
        bcur = bnxt; bnxt = bfut;
    }
    float* ob = out + (bbase + n0 + q * 4) * 128 + o0 + ml;
    #pragma unroll
    for (int r = 0; r < 4; ++r) ob[r * 128] = acc0[r] + bz;
    ob += 16 * 128;
    #pragma unroll
    for (int r = 0; r < 4; ++r) ob[r * 128] = acc1[r] + bz;
}

extern "C" void kernel_launch(void* const* d_in, const int* in_sizes, int n_in,
                              void* d_out, int out_size, void* d_ws, size_t ws_size,
                              hipStream_t stream)
{
    const float* inF  = (const float*)d_in[0];
    const int*   inds = (const int*)  d_in[1];
    const float* Wn   = (const float*)d_in[2];
    const float* addF = (const float*)d_in[3];
    const float* LW   = (const float*)d_in[4];
    const float* bias = (const float*)d_in[5];
    float* out = (float*)d_out;

    const bool f16p = (ws_size >= (size_t)WS_NEED);

    hipFuncSetAttribute((const void*)pconv_persistent,
                        hipFuncAttributeMaxDynamicSharedMemorySize, SPBYTES);
    hipFuncSetAttribute((const void*)pconv_fallback,
                        hipFuncAttributeMaxDynamicSharedMemorySize, SPBYTES_FB);

    if (f16p) {
        _Float16* LWB   = (_Float16*)d_ws;
        _Float16* inF16 = (_Float16*)((char*)d_ws + LWH_BYTES);
        cvt_lwb_kernel<<<dim3(128), dim3(256), 0, stream>>>(LW, LWB);
        cvt_inf_kernel<<<dim3((2 * NPTS * 64 + 255) / 256), dim3(256), 0, stream>>>(
            inF, inF16);
        pconv_persistent<<<dim3(NBLOCKS), dim3(512), SPBYTES, stream>>>(
            inF16, inds, Wn, addF, LWB, bias, out);
    } else {
        _Float16* LWh = (_Float16*)d_ws;
        cvt_lw_kernel<<<dim3(128), dim3(256), 0, stream>>>(LW, LWh);
        pconv_fallback<<<dim3(2 * NBLK), dim3(512), SPBYTES_FB, stream>>>(
            inF, inds, Wn, addF, LWh, bias, out);
    }
}